// Round 9
// baseline (68.864 us; speedup 1.0000x reference)
//
#include <hip/hip_runtime.h>
#include <hip/hip_fp16.h>
#include <math.h>

// Problem constants (from reference)
#define B_SZ 8192
#define L_SZ 50
#define D_SZ 128
#define C_SZ 256        // output cols of W_cpr
#define K_SZ 256        // = 2*D, GEMM K
#define R_SZ 7
#define V_SZ 100000
#define BR   32         // batch rows per block
#define NT   512        // 8 waves
#define NW   8          // waves per block

// ---------------------------------------------------------------------------
// Kernel A: convert emb f32 [V][128] -> fp16 table in ws. 77 MB streaming.
// ---------------------------------------------------------------------------
__global__ __launch_bounds__(256) void k_convert(const float* __restrict__ src,
                                                 __half* __restrict__ dst,
                                                 int n4) {
    int i = blockIdx.x * 256 + threadIdx.x;
    if (i >= n4) return;
    float4 v = ((const float4*)src)[i];
    union { __half2 h[2]; uint2 u; } pk;
    pk.h[0].x = __float2half_rn(v.x); pk.h[0].y = __float2half_rn(v.y);
    pk.h[1].x = __float2half_rn(v.z); pk.h[1].y = __float2half_rn(v.w);
    ((uint2*)dst)[i] = pk.u;
}

// ---------------------------------------------------------------------------
// Kernel B: transpose W_cpr [C][K] -> Wt [K][C], LDS-tiled. 256 KB, ~2 us.
// ---------------------------------------------------------------------------
__global__ __launch_bounds__(256) void k_transpose(const float* __restrict__ W,
                                                   float* __restrict__ Wt) {
    __shared__ float t[32][33];
    const int tx = threadIdx.x & 31;
    const int ty = threadIdx.x >> 5;  // 0..7
    const int k0 = blockIdx.x * 32;
    const int c0 = blockIdx.y * 32;
#pragma unroll
    for (int i = 0; i < 32; i += 8)
        t[ty + i][tx] = W[(size_t)(c0 + ty + i) * K_SZ + k0 + tx];
    __syncthreads();
#pragma unroll
    for (int i = 0; i < 32; i += 8)
        Wt[(size_t)(k0 + ty + i) * C_SZ + c0 + tx] = t[tx][ty + i];
}

// ---------------------------------------------------------------------------
// Fused kernel (fp16 table): gather + GEMM + LeakyReLU + head + log-softmax.
//
// vs R8:
//  * GEMM re-blocked to acc[8][2] (128 col-pairs x 4 row-groups): each W
//    element feeds 8 FMAs (was 4), W bytes/k-step halve, and a 1-deep W
//    register prefetch hides the ~220cy L2 latency under the FMA block.
//  * h is written back into X_lds after the k-loop (X fully consumed),
//    cutting LDS 82->48 KB -> 2 blocks/CU (gather/GEMM overlap across
//    blocks, 2x loads in flight). __launch_bounds__(512,4) pins VGPR<=128.
//  * Gather (compacted branch-free, 8x256B loads/iter) unchanged.
// ---------------------------------------------------------------------------
__global__ __launch_bounds__(512, 4) void k_fused_h(
    const int* __restrict__ ltok, const int* __restrict__ rtok,
    const int* __restrict__ lmask, const int* __restrict__ rmask,
    const __half* __restrict__ E16, const float* __restrict__ Wt,
    const float* __restrict__ b_cpr, const float* __restrict__ W_sm,
    const float* __restrict__ b_sm, float* __restrict__ out) {

    __shared__ float X_lds[BR][K_SZ];        // 32 KB (X, then reused for h)
    __shared__ int   ctok[NW][8][52];        // 13.3 KB compacted tokens
    __shared__ float part[BR][R_SZ][2];
    __shared__ float l_lds[BR][R_SZ];

    const int tid = threadIdx.x;
    const int wave = tid >> 6;
    const int lane = tid & 63;
    const int grp = lane >> 4;   // 16-lane group 0..3
    const int sub = lane & 15;   // float4 slot within a 256 B row
    const int row0 = blockIdx.x * BR;

    // ---------------- token load: 4 rows x 2 sides per wave ----------------
    const int rbase = row0 + wave * 4;
    int lt0 = 0, lt1 = 0, lt2 = 0, lt3 = 0;
    int rt0 = 0, rt1 = 0, rt2 = 0, rt3 = 0;
    int lm0 = 0, lm1 = 0, lm2 = 0, lm3 = 0;
    int rm0 = 0, rm1 = 0, rm2 = 0, rm3 = 0;
    if (lane < L_SZ) {
        const size_t o = (size_t)rbase * L_SZ + lane;
        lt0 = ltok[o];            lm0 = lmask[o];
        lt1 = ltok[o + L_SZ];     lm1 = lmask[o + L_SZ];
        lt2 = ltok[o + 2 * L_SZ]; lm2 = lmask[o + 2 * L_SZ];
        lt3 = ltok[o + 3 * L_SZ]; lm3 = lmask[o + 3 * L_SZ];
        rt0 = rtok[o];            rm0 = rmask[o];
        rt1 = rtok[o + L_SZ];     rm1 = rmask[o + L_SZ];
        rt2 = rtok[o + 2 * L_SZ]; rm2 = rmask[o + 2 * L_SZ];
        rt3 = rtok[o + 3 * L_SZ]; rm3 = rmask[o + 3 * L_SZ];
    }

    // ---------------- compact active tokens into LDS ----------------
    const unsigned long long ltm = (1ULL << lane) - 1;  // lanes below me
    int cnt[8];
#define COMPACT(s, m, t)                                               \
    {                                                                  \
        unsigned long long bal = __ballot((m) != 0);                   \
        cnt[s] = __popcll(bal);                                        \
        if ((m) != 0) ctok[wave][s][__popcll(bal & ltm)] = (t);        \
        if (lane == 0 && cnt[s] == 0) ctok[wave][s][0] = 0;            \
    }
    COMPACT(0, lm0, lt0) COMPACT(1, lm1, lt1)
    COMPACT(2, lm2, lt2) COMPACT(3, lm3, lt3)
    COMPACT(4, rm0, rt0) COMPACT(5, rm1, rt1)
    COMPACT(6, rm2, rt2) COMPACT(7, rm3, rt3)
#undef COMPACT

    int maxc = cnt[0];
#pragma unroll
    for (int s = 1; s < 8; ++s) maxc = max(maxc, cnt[s]);

    // ---------------- gather hot loop: branch-free, 8 loads/iter ----------
    const float4* E = (const float4*)E16;  // [V][16] float4 (8 halves each)
    float aL0[8] = {0}, aL1[8] = {0}, aL2[8] = {0}, aL3[8] = {0};
    float aR0[8] = {0}, aR1[8] = {0}, aR2[8] = {0}, aR3[8] = {0};

    const int nit = (maxc + 3) >> 2;
    for (int it = 0; it < nit; ++it) {
        const int idx = it * 4 + grp;
#define GATH(s, A)                                                      \
        {                                                               \
            int ii = min(idx, cnt[s] - 1); ii = (ii < 0) ? 0 : ii;      \
            const int t_ = ctok[wave][s][ii];                           \
            const float sc = (idx < cnt[s]) ? 1.f : 0.f;                \
            const float4 ev = E[((size_t)t_ << 4) + sub];               \
            const __half2* hp = (const __half2*)&ev;                    \
            _Pragma("unroll")                                           \
            for (int q = 0; q < 4; ++q) {                               \
                A[2 * q]     = fmaf(sc, __half2float(hp[q].x), A[2 * q]);     \
                A[2 * q + 1] = fmaf(sc, __half2float(hp[q].y), A[2 * q + 1]); \
            }                                                           \
        }
        GATH(0, aL0) GATH(1, aL1) GATH(2, aL2) GATH(3, aL3)
        GATH(4, aR0) GATH(5, aR1) GATH(6, aR2) GATH(7, aR3)
#undef GATH
    }

    // reduce across the 4 groups (lanes sharing `sub`)
#define RED(A)                                       \
    _Pragma("unroll")                                \
    for (int j = 0; j < 8; ++j) {                    \
        A[j] += __shfl_xor(A[j], 16);                \
        A[j] += __shfl_xor(A[j], 32);                \
    }
    RED(aL0) RED(aL1) RED(aL2) RED(aL3)
    RED(aR0) RED(aR1) RED(aR2) RED(aR3)
#undef RED

    // write X: row dims [0,128)=left, [128,256)=right; group g owns row g
    {
        const int r = wave * 4;
#define ST(A, row, side)                                                   \
        *(float4*)&X_lds[row][(side) * 128 + sub * 8] =                    \
            make_float4(A[0], A[1], A[2], A[3]);                           \
        *(float4*)&X_lds[row][(side) * 128 + sub * 8 + 4] =                \
            make_float4(A[4], A[5], A[6], A[7]);
        if (grp == 0)      { ST(aL0, r + 0, 0) ST(aR0, r + 0, 1) }
        else if (grp == 1) { ST(aL1, r + 1, 0) ST(aR1, r + 1, 1) }
        else if (grp == 2) { ST(aL2, r + 2, 0) ST(aR2, r + 2, 1) }
        else               { ST(aL3, r + 3, 0) ST(aR3, r + 3, 1) }
#undef ST
    }
    __syncthreads();

    // ---------------- GEMM phase: 128 col-pairs x 4 row-groups, R=8 --------
    const int cc = (tid & 127) * 2;       // 2 output cols
    const int rr = (tid >> 7) * 8;        // 8 rows
    float acc[8][2] = {{0.f}};
    float2 wb[4];
#pragma unroll
    for (int j = 0; j < 4; ++j)
        wb[j] = *(const float2*)&Wt[j * C_SZ + cc];

#define FMA_BLOCK(WREG)                                                \
    _Pragma("unroll")                                                  \
    for (int i = 0; i < 8; ++i) {                                      \
        float4 xv = *(const float4*)&X_lds[rr + i][k];                 \
        acc[i][0] = fmaf(xv.x, WREG[0].x, acc[i][0]);                  \
        acc[i][1] = fmaf(xv.x, WREG[0].y, acc[i][1]);                  \
        acc[i][0] = fmaf(xv.y, WREG[1].x, acc[i][0]);                  \
        acc[i][1] = fmaf(xv.y, WREG[1].y, acc[i][1]);                  \
        acc[i][0] = fmaf(xv.z, WREG[2].x, acc[i][0]);                  \
        acc[i][1] = fmaf(xv.z, WREG[2].y, acc[i][1]);                  \
        acc[i][0] = fmaf(xv.w, WREG[3].x, acc[i][0]);                  \
        acc[i][1] = fmaf(xv.w, WREG[3].y, acc[i][1]);                  \
    }

    for (int k = 0; k < K_SZ - 4; k += 4) {
        float2 wc[4];
#pragma unroll
        for (int j = 0; j < 4; ++j) wc[j] = wb[j];
#pragma unroll
        for (int j = 0; j < 4; ++j)
            wb[j] = *(const float2*)&Wt[(k + 4 + j) * C_SZ + cc];
        FMA_BLOCK(wc)
    }
    {
        const int k = K_SZ - 4;
        FMA_BLOCK(wb)
    }
#undef FMA_BLOCK

    __syncthreads();  // all X reads complete before h overwrites X_lds

    // bias + LeakyReLU -> h (aliased onto X_lds)
    {
        const float b0 = b_cpr[cc], b1 = b_cpr[cc + 1];
#pragma unroll
        for (int i = 0; i < 8; ++i) {
            float2 hv;
            hv.x = acc[i][0] + b0;
            hv.y = acc[i][1] + b1;
            hv.x = (hv.x >= 0.f) ? hv.x : 0.01f * hv.x;
            hv.y = (hv.y >= 0.f) ? hv.y : 0.01f * hv.y;
            *(float2*)&X_lds[rr + i][cc] = hv;
        }
    }
    __syncthreads();

    // ---------------- head: K-split partial dots (2 chunks of 128) --------
    if (tid < BR * R_SZ * 2) {            // 448 threads: (bl, r, chunk)
        const int chunk = tid & 1;
        const int rh = (tid >> 1) % R_SZ;
        const int bl = tid / (R_SZ * 2);
        const float* wr = W_sm + rh * C_SZ;
        const int c0 = chunk * 128;
        float s = 0.f;
#pragma unroll
        for (int c = 0; c < 128; c += 4) {
            float4 hv = *(const float4*)&X_lds[bl][c0 + c];
            s = fmaf(hv.x, wr[c0 + c + 0], s);
            s = fmaf(hv.y, wr[c0 + c + 1], s);
            s = fmaf(hv.z, wr[c0 + c + 2], s);
            s = fmaf(hv.w, wr[c0 + c + 3], s);
        }
        part[bl][rh][chunk] = s;
    }
    __syncthreads();

    if (tid < BR * R_SZ) {                // 224 threads: combine + bias
        const int bl = tid / R_SZ;
        const int rh = tid % R_SZ;
        l_lds[bl][rh] = part[bl][rh][0] + part[bl][rh][1] + b_sm[rh];
    }
    __syncthreads();

    // ---------------- log-softmax over R=7 ----------------
    if (tid < BR) {
        float m = -INFINITY;
#pragma unroll
        for (int rh = 0; rh < R_SZ; ++rh) m = fmaxf(m, l_lds[tid][rh]);
        float se = 0.f;
#pragma unroll
        for (int rh = 0; rh < R_SZ; ++rh) se += expf(l_lds[tid][rh] - m);
        const float lse = m + logf(se);
        const size_t ob = (size_t)(row0 + tid) * R_SZ;
#pragma unroll
        for (int rh = 0; rh < R_SZ; ++rh) out[ob + rh] = l_lds[tid][rh] - lse;
    }
}

// ---------------------------------------------------------------------------
extern "C" void kernel_launch(void* const* d_in, const int* in_sizes, int n_in,
                              void* d_out, int out_size, void* d_ws, size_t ws_size,
                              hipStream_t stream) {
    const int* ltok = (const int*)d_in[0];
    const int* rtok = (const int*)d_in[1];
    const int* lmask = (const int*)d_in[2];
    const int* rmask = (const int*)d_in[3];
    const float* emb = (const float*)d_in[4];
    const float* W_cpr = (const float*)d_in[5];
    const float* b_cpr = (const float*)d_in[6];
    const float* W_sm = (const float*)d_in[7];
    const float* b_sm = (const float*)d_in[8];
    float* out = (float*)d_out;

    const size_t E16_BYTES = (size_t)V_SZ * D_SZ * sizeof(__half);  // 25.6 MB
    __half* E16 = (__half*)d_ws;
    float* Wt = (float*)((char*)d_ws + E16_BYTES);                  // 256 KB

    const int n4 = V_SZ * D_SZ / 4;
    k_convert<<<(n4 + 255) / 256, 256, 0, stream>>>(emb, E16, n4);
    k_transpose<<<dim3(K_SZ / 32, C_SZ / 32), 256, 0, stream>>>(W_cpr, Wt);
    k_fused_h<<<B_SZ / BR, NT, 0, stream>>>(ltok, rtok, lmask, rmask, E16,
                                            Wt, b_cpr, W_sm, b_sm, out);
}